// Round 1
// baseline (121.649 us; speedup 1.0000x reference)
//
#include <hip/hip_runtime.h>

// L2-distance causal attention with zero-KV sink.
// B=2, H=16, N=2048, D=64. fp32 in/out, bf16 MFMA internally.
//
// Math: out_i = [ sum_{j<=i} exp2(s_ij - m) * v_j ] / [ exp2(-m) + sum exp2(s_ij - m) ]
//   s_ij = QS*(q_i . k_j) + bias_j,  QS = 2*log2e/sqrt(66),  bias_j = -log2e/sqrt(66)*|k_j|^2
// (sink logit == 0 after the shift-invariant -|q|^2 drop)

#define NQ 2048
#define DH 64

typedef float f32x4 __attribute__((ext_vector_type(4)));
typedef __bf16 bf16x8 __attribute__((ext_vector_type(8)));
typedef unsigned short u16x8 __attribute__((ext_vector_type(8)));

union B8 { u16x8 u; bf16x8 b; };

__device__ __forceinline__ unsigned short f2b(float f) {
  unsigned int x = __builtin_bit_cast(unsigned int, f);
  unsigned int r = x + 0x7fffu + ((x >> 16) & 1u);   // RNE to bf16
  return (unsigned short)(r >> 16);
}
__device__ __forceinline__ float b2f(unsigned short u) {
  unsigned int t = ((unsigned int)u) << 16;
  return __builtin_bit_cast(float, t);
}

// K-slot permutation: slot s (bits c1 c0 g1 g0 r1 r0) holds key (c1 g1 g0 c0 r1 r0).
// This makes QK^T's C-layout scores be exactly the PV B-fragment values (no exchange).
// Inverse (key -> slot), used at staging time:
__device__ __forceinline__ int kslot(int a) {
  return (a & 0x23) | ((a & 0x04) << 2) | ((a & 0x18) >> 1);
}

__global__ __launch_bounds__(256) void attend_l2_flash(
    const float* __restrict__ q, const float* __restrict__ k,
    const float* __restrict__ v, float* __restrict__ out)
{
  const int bh   = blockIdx.x;
  const int qt   = (gridDim.y - 1) - blockIdx.y;   // heavy tiles dispatch first
  const int qbase = qt * 64;
  const int tid  = threadIdx.x;
  const int wid  = tid >> 6;
  const int lane = tid & 63;
  const int g    = lane >> 4;
  const int qi   = lane & 15;
  const int qg   = qbase + wid * 16 + qi;          // this lane's query row
  const size_t bhN = (size_t)bh * NQ;

  __shared__ __align__(16) unsigned short sK[64 * 64]; // [slot][d^((slot&7)<<3)] bf16
  __shared__ __align__(16) unsigned short sV[64 * 64]; // V^T: [d][kv^((d&7)<<3)] bf16
  __shared__ __align__(16) float sBias[64];            // -BS*|k_bf|^2, slot-permuted

  constexpr float QS = 0.3551784733906239f;   // 2*log2(e)/sqrt(66)
  constexpr float BS = 0.17758923669531197f;  // log2(e)/sqrt(66)

  // ---- Q fragments (hi/lo split), hoisted out of the KV loop ----
  const float* qrow = q + (bhN + qg) * DH;
  bf16x8 qhi[2], qlo[2];
#pragma unroll
  for (int ks = 0; ks < 2; ks++) {
    B8 th, tl;
#pragma unroll
    for (int j = 0; j < 8; j++) {
      float x = qrow[ks * 32 + g * 8 + j] * QS;
      unsigned short h = f2b(x);
      th.u[j] = h;
      tl.u[j] = f2b(x - b2f(h));
    }
    qhi[ks] = th.b; qlo[ks] = tl.b;
  }

  f32x4 oacc[4] = { {0,0,0,0}, {0,0,0,0}, {0,0,0,0}, {0,0,0,0} }; // O^T, 4 d-blocks
  float m = 0.0f;   // running max in base-2 logit units (sink => m >= 0 always)
  float l = 0.0f;   // per-lane partial denominator (sink added at the end)

  const int ntiles = qt + 1;
  for (int t = 0; t < ntiles; t++) {
    const int tile64 = t * 64;

    // ---- stage K tile (+ per-key bias), slot-permuted, XOR-swizzled ----
#pragma unroll
    for (int i = 0; i < 4; i++) {
      int f  = i * 256 + tid;
      int kg = f >> 4, d4 = f & 15;
      int slot = kslot(kg);
      const float4* kp = (const float4*)(k + (bhN + tile64 + kg) * DH);
      float4 kk = kp[d4];
      unsigned short h0 = f2b(kk.x), h1 = f2b(kk.y), h2 = f2b(kk.z), h3 = f2b(kk.w);
      float a0 = b2f(h0), a1 = b2f(h1), a2 = b2f(h2), a3 = b2f(h3);
      float ss = a0*a0 + a1*a1 + a2*a2 + a3*a3;  // |k_bf|^2 partial (consistent w/ MFMA)
      ss += __shfl_xor(ss, 1, 64);
      ss += __shfl_xor(ss, 2, 64);
      ss += __shfl_xor(ss, 4, 64);
      ss += __shfl_xor(ss, 8, 64);
      if (d4 == 0) sBias[slot] = -BS * ss;
      unsigned int w0 = (unsigned int)h0 | ((unsigned int)h1 << 16);
      unsigned int w1 = (unsigned int)h2 | ((unsigned int)h3 << 16);
      int idx = slot * 64 + ((d4 * 4) ^ ((slot & 7) << 3));
      uint2 wv; wv.x = w0; wv.y = w1;
      *(uint2*)&sK[idx] = wv;
    }

    // ---- stage V^T (identity slot order), coalesced column loads ----
#pragma unroll
    for (int jj = 0; jj < 4; jj++) {
      int kgb = jj * 16 + wid * 4;
      const float* vp = v + (bhN + tile64 + kgb) * DH + lane;
      float x0 = vp[0], x1 = vp[DH], x2 = vp[2 * DH], x3 = vp[3 * DH];
      unsigned int w0 = (unsigned int)f2b(x0) | ((unsigned int)f2b(x1) << 16);
      unsigned int w1 = (unsigned int)f2b(x2) | ((unsigned int)f2b(x3) << 16);
      int idx = lane * 64 + (kgb ^ ((lane & 7) << 3));
      uint2 wv; wv.x = w0; wv.y = w1;
      *(uint2*)&sV[idx] = wv;
    }
    __syncthreads();

    // ---- QK^T, swapped: S^T = K . Q^T  (C: col=query, rows=key slots) ----
    f32x4 sc[4] = { {0,0,0,0}, {0,0,0,0}, {0,0,0,0}, {0,0,0,0} };
#pragma unroll
    for (int c = 0; c < 4; c++) {
#pragma unroll
      for (int ks = 0; ks < 2; ks++) {
        int idx = (16 * c + qi) * 64 + ((ks * 32 + g * 8) ^ ((qi & 7) << 3));
        bf16x8 ak = *(const bf16x8*)&sK[idx];
        sc[c] = __builtin_amdgcn_mfma_f32_16x16x32_bf16(ak, qhi[ks], sc[c], 0, 0, 0);
        sc[c] = __builtin_amdgcn_mfma_f32_16x16x32_bf16(ak, qlo[ks], sc[c], 0, 0, 0);
      }
    }

    // ---- online softmax (lane-local; reduce only across the 4 row-groups) ----
    const bool diag = (t == qt);
    float p[4][4];
    float mt = -1e30f;
#pragma unroll
    for (int c = 0; c < 4; c++) {
      f32x4 bb = *(const f32x4*)&sBias[16 * c + 4 * g];
#pragma unroll
      for (int r = 0; r < 4; r++) {
        float s = sc[c][r] + bb[r];
        if (diag) {
          int key = tile64 + 32 * (c >> 1) + 8 * g + 4 * (c & 1) + r; // pi(slot)
          if (key > qg) s = -1e30f;
        }
        p[c][r] = s;
        mt = fmaxf(mt, s);
      }
    }
    mt = fmaxf(mt, __shfl_xor(mt, 16, 64));
    mt = fmaxf(mt, __shfl_xor(mt, 32, 64));
    float mn = fmaxf(m, mt);
    float alpha = exp2f(m - mn);
    m = mn;
    l *= alpha;
#pragma unroll
    for (int c = 0; c < 4; c++)
#pragma unroll
      for (int r = 0; r < 4; r++) {
        float e = exp2f(p[c][r] - m);
        p[c][r] = e;
        l += e;
      }
#pragma unroll
    for (int db = 0; db < 4; db++) oacc[db] *= alpha;

    // ---- P fragments: by construction of the slot permutation, local repack ----
    B8 t0, t1;
#pragma unroll
    for (int j = 0; j < 8; j++) {
      t0.u[j] = f2b(p[(j >> 2)][j & 3]);       // ks=0: c = 0 + (j>>2)
      t1.u[j] = f2b(p[2 + (j >> 2)][j & 3]);   // ks=1: c = 2 + (j>>2)
    }

    // ---- PV: O^T += V^T . P^T ----
#pragma unroll
    for (int db = 0; db < 4; db++) {
#pragma unroll
      for (int ks = 0; ks < 2; ks++) {
        int idx = (db * 16 + qi) * 64 + ((ks * 32 + g * 8) ^ ((qi & 7) << 3));
        bf16x8 av = *(const bf16x8*)&sV[idx];
        oacc[db] = __builtin_amdgcn_mfma_f32_16x16x32_bf16(av, (ks ? t1.b : t0.b),
                                                           oacc[db], 0, 0, 0);
      }
    }
    __syncthreads();
  }

  // ---- epilogue: denominator (+ sink weight exp2(-m)), scaled store ----
  float lt = l;
  lt += __shfl_xor(lt, 16, 64);
  lt += __shfl_xor(lt, 32, 64);
  float denom = lt + exp2f(-m);
  float inv = 1.0f / denom;
  float* op = out + (bhN + qg) * DH;
#pragma unroll
  for (int db = 0; db < 4; db++) {
    float4 o;
    o.x = oacc[db][0] * inv;
    o.y = oacc[db][1] * inv;
    o.z = oacc[db][2] * inv;
    o.w = oacc[db][3] * inv;
    *(float4*)(op + db * 16 + 4 * g) = o;  // d = db*16 + 4g + r
  }
}

extern "C" void kernel_launch(void* const* d_in, const int* in_sizes, int n_in,
                              void* d_out, int out_size, void* d_ws, size_t ws_size,
                              hipStream_t stream) {
  (void)in_sizes; (void)n_in; (void)d_ws; (void)ws_size; (void)out_size;
  const float* q = (const float*)d_in[0];
  const float* k = (const float*)d_in[1];
  const float* v = (const float*)d_in[2];
  float* out = (float*)d_out;
  dim3 grid(32, 32);  // x = b*h, y = query tile (reversed inside kernel)
  attend_l2_flash<<<grid, dim3(256), 0, stream>>>(q, k, v, out);
}

// Round 2
// 64.413 us; speedup vs baseline: 1.8886x; 1.8886x over previous
//
#include <hip/hip_runtime.h>

// L2-distance causal attention with zero-KV sink.
// B=2, H=16, N=2048, D=64. fp32 in/out, bf16 MFMA internally.
//
// Round 2 structure:
//   Kernel 1 (build_ws): one-shot conversion of K/V into per-tile LDS byte
//     images (bf16, slot-permuted + XOR-swizzled K; transposed + swizzled V^T)
//     plus the per-key bias  -BS*|k_bf|^2, stored in d_ws.
//   Kernel 2 (attend): flash loop; stages each tile image with
//     global_load_lds width=16 (linear copy), double-buffered, one barrier
//     per tile. Softmax fully in-register via swapped QK^T + slot permutation.

#define NQ 2048
#define DH 64
#define NT 32   // KV tiles per sequence (2048/64)

typedef float f32x4 __attribute__((ext_vector_type(4)));
typedef __bf16 bf16x8 __attribute__((ext_vector_type(8)));
typedef unsigned short u16x8 __attribute__((ext_vector_type(8)));

union B8 { u16x8 u; bf16x8 b; };

__device__ __forceinline__ unsigned short f2b(float f) {
  unsigned int x = __builtin_bit_cast(unsigned int, f);
  unsigned int r = x + 0x7fffu + ((x >> 16) & 1u);   // RNE to bf16
  return (unsigned short)(r >> 16);
}
__device__ __forceinline__ float b2f(unsigned short u) {
  unsigned int t = ((unsigned int)u) << 16;
  return __builtin_bit_cast(float, t);
}

// K-slot permutation: slot s (bits c1 c0 g1 g0 r1 r0) holds key (c1 g1 g0 c0 r1 r0).
// Makes QK^T's C-layout scores be exactly the PV B-fragment values (no exchange).
__device__ __forceinline__ int kslot(int a) {
  return (a & 0x23) | ((a & 0x04) << 2) | ((a & 0x18) >> 1);
}

__device__ __forceinline__ void gl_lds16(const void* g, void* l) {
  __builtin_amdgcn_global_load_lds(
      (const __attribute__((address_space(1))) unsigned int*)g,
      (__attribute__((address_space(3))) unsigned int*)l, 16, 0, 0);
}
__device__ __forceinline__ void gl_lds4(const void* g, void* l) {
  __builtin_amdgcn_global_load_lds(
      (const __attribute__((address_space(1))) unsigned int*)g,
      (__attribute__((address_space(3))) unsigned int*)l, 4, 0, 0);
}

constexpr float QS = 0.3551784733906239f;   // 2*log2(e)/sqrt(66)
constexpr float BS = 0.17758923669531197f;  // log2(e)/sqrt(66)

// ---------------- kernel 1: build per-tile images ----------------
__global__ __launch_bounds__(256) void build_ws(
    const float* __restrict__ k, const float* __restrict__ v,
    unsigned short* __restrict__ wsK, unsigned short* __restrict__ wsV,
    float* __restrict__ wsB)
{
  const int bh = blockIdx.x;          // 0..31
  const int t  = blockIdx.y;          // 0..31
  const int tid  = threadIdx.x;
  const int wid  = tid >> 6;
  const int lane = tid & 63;
  const size_t bhN = (size_t)bh * NQ;
  const int tile64 = t * 64;
  const size_t tileId = (size_t)bh * NT + t;
  unsigned short* Kt = wsK + tileId * 4096;
  unsigned short* Vt = wsV + tileId * 4096;
  float*          Bt = wsB + tileId * 64;

  // K image (+ bias), slot-permuted, XOR-swizzled — exact LDS byte image.
#pragma unroll
  for (int i = 0; i < 4; i++) {
    int f  = i * 256 + tid;
    int kg = f >> 4, d4 = f & 15;
    int slot = kslot(kg);
    const float4* kp = (const float4*)(k + (bhN + tile64 + kg) * DH);
    float4 kk = kp[d4];
    unsigned short h0 = f2b(kk.x), h1 = f2b(kk.y), h2 = f2b(kk.z), h3 = f2b(kk.w);
    float a0 = b2f(h0), a1 = b2f(h1), a2 = b2f(h2), a3 = b2f(h3);
    float ss = a0*a0 + a1*a1 + a2*a2 + a3*a3;     // |k_bf|^2 partial
    ss += __shfl_xor(ss, 1, 64);
    ss += __shfl_xor(ss, 2, 64);
    ss += __shfl_xor(ss, 4, 64);
    ss += __shfl_xor(ss, 8, 64);
    if (d4 == 0) Bt[slot] = -BS * ss;
    unsigned int w0 = (unsigned int)h0 | ((unsigned int)h1 << 16);
    unsigned int w1 = (unsigned int)h2 | ((unsigned int)h3 << 16);
    int idx = slot * 64 + ((d4 * 4) ^ ((slot & 7) << 3));
    uint2 wv; wv.x = w0; wv.y = w1;
    *(uint2*)&Kt[idx] = wv;
  }

  // V^T image (identity slot order), XOR-swizzled.
#pragma unroll
  for (int jj = 0; jj < 4; jj++) {
    int kgb = jj * 16 + wid * 4;
    const float* vp = v + (bhN + tile64 + kgb) * DH + lane;
    float x0 = vp[0], x1 = vp[DH], x2 = vp[2 * DH], x3 = vp[3 * DH];
    unsigned int w0 = (unsigned int)f2b(x0) | ((unsigned int)f2b(x1) << 16);
    unsigned int w1 = (unsigned int)f2b(x2) | ((unsigned int)f2b(x3) << 16);
    int idx = lane * 64 + (kgb ^ ((lane & 7) << 3));
    uint2 wv; wv.x = w0; wv.y = w1;
    *(uint2*)&Vt[idx] = wv;
  }
}

// ---------------- kernel 2: flash attention over premade images ----------------
__global__ __launch_bounds__(256) void attend_l2_flash(
    const float* __restrict__ q,
    const unsigned short* __restrict__ wsK,
    const unsigned short* __restrict__ wsV,
    const float* __restrict__ wsB,
    float* __restrict__ out)
{
  const int bh   = blockIdx.x;
  const int qt   = (gridDim.y - 1) - blockIdx.y;   // heavy tiles dispatch first
  const int qbase = qt * 64;
  const int tid  = threadIdx.x;
  const int wid  = tid >> 6;
  const int lane = tid & 63;
  const int g    = lane >> 4;
  const int qi   = lane & 15;
  const int qg   = qbase + wid * 16 + qi;          // this lane's query row
  const size_t bhN = (size_t)bh * NQ;

  __shared__ __align__(16) unsigned short sK[2][4096];
  __shared__ __align__(16) unsigned short sV[2][4096];
  __shared__ __align__(16) float sB[2][64];

  // ---- Q fragments (hi/lo split), hoisted ----
  const float* qrow = q + (bhN + qg) * DH;
  bf16x8 qhi[2], qlo[2];
#pragma unroll
  for (int ks = 0; ks < 2; ks++) {
    B8 th, tl;
#pragma unroll
    for (int j = 0; j < 8; j++) {
      float x = qrow[ks * 32 + g * 8 + j] * QS;
      unsigned short h = f2b(x);
      th.u[j] = h;
      tl.u[j] = f2b(x - b2f(h));
    }
    qhi[ks] = th.b; qlo[ks] = tl.b;
  }

  f32x4 oacc[4] = { {0,0,0,0}, {0,0,0,0}, {0,0,0,0}, {0,0,0,0} };
  float m = 0.0f;   // running max (base-2 logit units; sink => m >= 0)
  float l = 0.0f;   // per-lane partial denominator

  const int ntiles = qt + 1;
  const size_t tbase = (size_t)bh * NT;

  // stage tile t into buffer buf (pure linear DMA; images premade)
  auto STAGE = [&](int buf, int t) {
    const char* Kt = (const char*)(wsK + (tbase + t) * 4096);
    const char* Vt = (const char*)(wsV + (tbase + t) * 4096);
#pragma unroll
    for (int c = 0; c < 2; c++) {
      int boff = wid * 2048 + c * 1024;
      gl_lds16(Kt + boff + lane * 16, (char*)&sK[buf][0] + boff);
      gl_lds16(Vt + boff + lane * 16, (char*)&sV[buf][0] + boff);
    }
    if (wid == 0) {
      const char* Bt = (const char*)(wsB + (tbase + t) * 64);
      gl_lds4(Bt + lane * 4, (char*)&sB[buf][0]);
    }
  };

  int cur = 0;
  STAGE(0, 0);
  __syncthreads();

  for (int t = 0; t < ntiles; t++) {
    if (t + 1 < ntiles) STAGE(cur ^ 1, t + 1);

    // ---- QK^T, swapped: S^T = K . Q^T ----
    f32x4 sc[4] = { {0,0,0,0}, {0,0,0,0}, {0,0,0,0}, {0,0,0,0} };
#pragma unroll
    for (int c = 0; c < 4; c++) {
#pragma unroll
      for (int ks = 0; ks < 2; ks++) {
        int idx = (16 * c + qi) * 64 + ((ks * 32 + g * 8) ^ ((qi & 7) << 3));
        bf16x8 ak = *(const bf16x8*)&sK[cur][idx];
        sc[c] = __builtin_amdgcn_mfma_f32_16x16x32_bf16(ak, qhi[ks], sc[c], 0, 0, 0);
        sc[c] = __builtin_amdgcn_mfma_f32_16x16x32_bf16(ak, qlo[ks], sc[c], 0, 0, 0);
      }
    }

    // ---- online softmax (lane-local + 2 shfl) ----
    const bool diag = (t == ntiles - 1);
    const int tile64 = t * 64;
    float p[4][4];
    float mt = -1e30f;
#pragma unroll
    for (int c = 0; c < 4; c++) {
      f32x4 bb = *(const f32x4*)&sB[cur][16 * c + 4 * g];
#pragma unroll
      for (int r = 0; r < 4; r++) {
        float s = sc[c][r] + bb[r];
        if (diag) {
          int key = tile64 + 32 * (c >> 1) + 8 * g + 4 * (c & 1) + r; // pi(slot)
          if (key > qg) s = -1e30f;
        }
        p[c][r] = s;
        mt = fmaxf(mt, s);
      }
    }
    mt = fmaxf(mt, __shfl_xor(mt, 16, 64));
    mt = fmaxf(mt, __shfl_xor(mt, 32, 64));
    float mn = fmaxf(m, mt);
    float alpha = exp2f(m - mn);
    m = mn;
    l *= alpha;
#pragma unroll
    for (int c = 0; c < 4; c++)
#pragma unroll
      for (int r = 0; r < 4; r++) {
        float e = exp2f(p[c][r] - m);
        p[c][r] = e;
        l += e;
      }
#pragma unroll
    for (int db = 0; db < 4; db++) oacc[db] *= alpha;

    // ---- P repack (local by slot-permutation construction) ----
    B8 t0, t1;
#pragma unroll
    for (int j = 0; j < 8; j++) {
      t0.b[j] = (__bf16)p[(j >> 2)][j & 3];
      t1.b[j] = (__bf16)p[2 + (j >> 2)][j & 3];
    }

    // ---- PV: O^T += V^T . P^T ----
#pragma unroll
    for (int db = 0; db < 4; db++) {
#pragma unroll
      for (int ks = 0; ks < 2; ks++) {
        int idx = (db * 16 + qi) * 64 + ((ks * 32 + g * 8) ^ ((qi & 7) << 3));
        bf16x8 av = *(const bf16x8*)&sV[cur][idx];
        oacc[db] = __builtin_amdgcn_mfma_f32_16x16x32_bf16(av, (ks ? t1.b : t0.b),
                                                           oacc[db], 0, 0, 0);
      }
    }
    __syncthreads();   // drains vmcnt (next tile landed) + LDS-read reuse fence
    cur ^= 1;
  }

  // ---- epilogue ----
  float lt = l;
  lt += __shfl_xor(lt, 16, 64);
  lt += __shfl_xor(lt, 32, 64);
  float denom = lt + exp2f(-m);   // + sink weight
  float inv = 1.0f / denom;
  float* op = out + (bhN + qg) * DH;
#pragma unroll
  for (int db = 0; db < 4; db++) {
    float4 o;
    o.x = oacc[db][0] * inv;
    o.y = oacc[db][1] * inv;
    o.z = oacc[db][2] * inv;
    o.w = oacc[db][3] * inv;
    *(float4*)(op + db * 16 + 4 * g) = o;
  }
}

extern "C" void kernel_launch(void* const* d_in, const int* in_sizes, int n_in,
                              void* d_out, int out_size, void* d_ws, size_t ws_size,
                              hipStream_t stream) {
  (void)in_sizes; (void)n_in; (void)out_size; (void)ws_size;
  const float* q = (const float*)d_in[0];
  const float* k = (const float*)d_in[1];
  const float* v = (const float*)d_in[2];
  float* out = (float*)d_out;

  // ws layout: K images 8 MiB | V images 8 MiB | bias 256 KiB
  char* ws = (char*)d_ws;
  unsigned short* wsK = (unsigned short*)ws;
  unsigned short* wsV = (unsigned short*)(ws + (8u << 20));
  float*          wsB = (float*)(ws + (16u << 20));

  build_ws<<<dim3(32, NT), dim3(256), 0, stream>>>(k, v, wsK, wsV, wsB);
  attend_l2_flash<<<dim3(32, NT), dim3(256), 0, stream>>>(q, wsK, wsV, wsB, out);
}

// Round 3
// 62.099 us; speedup vs baseline: 1.9590x; 1.0373x over previous
//
#include <hip/hip_runtime.h>

// L2-distance causal attention with zero-KV sink.
// B=2, H=16, N=2048, D=64. fp32 in/out, bf16 MFMA internally.
//
// Structure:
//   Kernel 1 (build_ws): one-shot conversion of K/V into per-tile LDS byte
//     images (bf16, slot-permuted + XOR-swizzled K; transposed + swizzled V^T)
//     plus the per-key bias  -BS*|k_bf|^2, stored in d_ws.
//   Kernel 2 (attend): flash loop; stages each tile image with
//     global_load_lds width=16 (linear copy), double-buffered, one barrier
//     per tile. Softmax fully in-register via swapped QK^T + slot permutation.
//   Round 3: softmax VALU diet — exact defer-max (sink pins m=0, rescale
//     almost never fires), m==0 fast path, packed f32 (v_pk_*) arithmetic,
//     max3 tree, no cross-lane ops in the hot path.

#define NQ 2048
#define DH 64
#define NT 32   // KV tiles per sequence (2048/64)

typedef float f32x4 __attribute__((ext_vector_type(4)));
typedef __bf16 bf16x8 __attribute__((ext_vector_type(8)));
typedef unsigned short u16x8 __attribute__((ext_vector_type(8)));

union B8 { u16x8 u; bf16x8 b; };

__device__ __forceinline__ unsigned short f2b(float f) {
  unsigned int x = __builtin_bit_cast(unsigned int, f);
  unsigned int r = x + 0x7fffu + ((x >> 16) & 1u);   // RNE to bf16
  return (unsigned short)(r >> 16);
}
__device__ __forceinline__ float b2f(unsigned short u) {
  unsigned int t = ((unsigned int)u) << 16;
  return __builtin_bit_cast(float, t);
}
__device__ __forceinline__ f32x4 vmax4(f32x4 a, f32x4 b) {
  f32x4 r;
  r[0] = fmaxf(a[0], b[0]); r[1] = fmaxf(a[1], b[1]);
  r[2] = fmaxf(a[2], b[2]); r[3] = fmaxf(a[3], b[3]);
  return r;
}

// K-slot permutation: slot s (bits c1 c0 g1 g0 r1 r0) holds key (c1 g1 g0 c0 r1 r0).
// Makes QK^T's C-layout scores be exactly the PV B-fragment values (no exchange).
__device__ __forceinline__ int kslot(int a) {
  return (a & 0x23) | ((a & 0x04) << 2) | ((a & 0x18) >> 1);
}

__device__ __forceinline__ void gl_lds16(const void* g, void* l) {
  __builtin_amdgcn_global_load_lds(
      (const __attribute__((address_space(1))) unsigned int*)g,
      (__attribute__((address_space(3))) unsigned int*)l, 16, 0, 0);
}
__device__ __forceinline__ void gl_lds4(const void* g, void* l) {
  __builtin_amdgcn_global_load_lds(
      (const __attribute__((address_space(1))) unsigned int*)g,
      (__attribute__((address_space(3))) unsigned int*)l, 4, 0, 0);
}

constexpr float QS = 0.3551784733906239f;   // 2*log2(e)/sqrt(66)
constexpr float BS = 0.17758923669531197f;  // log2(e)/sqrt(66)

// ---------------- kernel 1: build per-tile images ----------------
__global__ __launch_bounds__(256) void build_ws(
    const float* __restrict__ k, const float* __restrict__ v,
    unsigned short* __restrict__ wsK, unsigned short* __restrict__ wsV,
    float* __restrict__ wsB)
{
  const int bh = blockIdx.x;          // 0..31
  const int t  = blockIdx.y;          // 0..31
  const int tid  = threadIdx.x;
  const int wid  = tid >> 6;
  const int lane = tid & 63;
  const size_t bhN = (size_t)bh * NQ;
  const int tile64 = t * 64;
  const size_t tileId = (size_t)bh * NT + t;
  unsigned short* Kt = wsK + tileId * 4096;
  unsigned short* Vt = wsV + tileId * 4096;
  float*          Bt = wsB + tileId * 64;

  // K image (+ bias), slot-permuted, XOR-swizzled — exact LDS byte image.
#pragma unroll
  for (int i = 0; i < 4; i++) {
    int f  = i * 256 + tid;
    int kg = f >> 4, d4 = f & 15;
    int slot = kslot(kg);
    const float4* kp = (const float4*)(k + (bhN + tile64 + kg) * DH);
    float4 kk = kp[d4];
    unsigned short h0 = f2b(kk.x), h1 = f2b(kk.y), h2 = f2b(kk.z), h3 = f2b(kk.w);
    float a0 = b2f(h0), a1 = b2f(h1), a2 = b2f(h2), a3 = b2f(h3);
    float ss = a0*a0 + a1*a1 + a2*a2 + a3*a3;     // |k_bf|^2 partial
    ss += __shfl_xor(ss, 1, 64);
    ss += __shfl_xor(ss, 2, 64);
    ss += __shfl_xor(ss, 4, 64);
    ss += __shfl_xor(ss, 8, 64);
    if (d4 == 0) Bt[slot] = -BS * ss;
    unsigned int w0 = (unsigned int)h0 | ((unsigned int)h1 << 16);
    unsigned int w1 = (unsigned int)h2 | ((unsigned int)h3 << 16);
    int idx = slot * 64 + ((d4 * 4) ^ ((slot & 7) << 3));
    uint2 wv; wv.x = w0; wv.y = w1;
    *(uint2*)&Kt[idx] = wv;
  }

  // V^T image (identity slot order), XOR-swizzled.
#pragma unroll
  for (int jj = 0; jj < 4; jj++) {
    int kgb = jj * 16 + wid * 4;
    const float* vp = v + (bhN + tile64 + kgb) * DH + lane;
    float x0 = vp[0], x1 = vp[DH], x2 = vp[2 * DH], x3 = vp[3 * DH];
    unsigned int w0 = (unsigned int)f2b(x0) | ((unsigned int)f2b(x1) << 16);
    unsigned int w1 = (unsigned int)f2b(x2) | ((unsigned int)f2b(x3) << 16);
    int idx = lane * 64 + (kgb ^ ((lane & 7) << 3));
    uint2 wv; wv.x = w0; wv.y = w1;
    *(uint2*)&Vt[idx] = wv;
  }
}

// ---------------- kernel 2: flash attention over premade images ----------------
__global__ __launch_bounds__(256) void attend_l2_flash(
    const float* __restrict__ q,
    const unsigned short* __restrict__ wsK,
    const unsigned short* __restrict__ wsV,
    const float* __restrict__ wsB,
    float* __restrict__ out)
{
  const int bh   = blockIdx.x;
  const int qt   = (gridDim.y - 1) - blockIdx.y;   // heavy tiles dispatch first
  const int qbase = qt * 64;
  const int tid  = threadIdx.x;
  const int wid  = tid >> 6;
  const int lane = tid & 63;
  const int g    = lane >> 4;
  const int qi   = lane & 15;
  const int qg   = qbase + wid * 16 + qi;          // this lane's query row
  const size_t bhN = (size_t)bh * NQ;

  __shared__ __align__(16) unsigned short sK[2][4096];
  __shared__ __align__(16) unsigned short sV[2][4096];
  __shared__ __align__(16) float sB[2][64];

  // ---- Q fragments (hi/lo split), hoisted ----
  const float* qrow = q + (bhN + qg) * DH;
  bf16x8 qhi[2], qlo[2];
#pragma unroll
  for (int ks = 0; ks < 2; ks++) {
    B8 th, tl;
#pragma unroll
    for (int j = 0; j < 8; j++) {
      float x = qrow[ks * 32 + g * 8 + j] * QS;
      unsigned short h = f2b(x);
      th.u[j] = h;
      tl.u[j] = f2b(x - b2f(h));
    }
    qhi[ks] = th.b; qlo[ks] = tl.b;
  }

  f32x4 oacc[4] = { {0,0,0,0}, {0,0,0,0}, {0,0,0,0}, {0,0,0,0} };
  float m = 0.0f;                 // running max (base-2; sink pins m >= 0)
  f32x4 l4 = {0, 0, 0, 0};        // packed partial denominator

  const int ntiles = qt + 1;
  const size_t tbase = (size_t)bh * NT;

  auto STAGE = [&](int buf, int t) {
    const char* Kt = (const char*)(wsK + (tbase + t) * 4096);
    const char* Vt = (const char*)(wsV + (tbase + t) * 4096);
#pragma unroll
    for (int c = 0; c < 2; c++) {
      int boff = wid * 2048 + c * 1024;
      gl_lds16(Kt + boff + lane * 16, (char*)&sK[buf][0] + boff);
      gl_lds16(Vt + boff + lane * 16, (char*)&sV[buf][0] + boff);
    }
    if (wid == 0) {
      const char* Bt = (const char*)(wsB + (tbase + t) * 64);
      gl_lds4(Bt + lane * 4, (char*)&sB[buf][0]);
    }
  };

  int cur = 0;
  STAGE(0, 0);
  __syncthreads();

  for (int t = 0; t < ntiles; t++) {
    if (t + 1 < ntiles) STAGE(cur ^ 1, t + 1);

    // ---- QK^T, swapped: S^T = K . Q^T ----
    f32x4 sc[4] = { {0,0,0,0}, {0,0,0,0}, {0,0,0,0}, {0,0,0,0} };
#pragma unroll
    for (int c = 0; c < 4; c++) {
#pragma unroll
      for (int ks = 0; ks < 2; ks++) {
        int idx = (16 * c + qi) * 64 + ((ks * 32 + g * 8) ^ ((qi & 7) << 3));
        bf16x8 ak = *(const bf16x8*)&sK[cur][idx];
        sc[c] = __builtin_amdgcn_mfma_f32_16x16x32_bf16(ak, qhi[ks], sc[c], 0, 0, 0);
        sc[c] = __builtin_amdgcn_mfma_f32_16x16x32_bf16(ak, qlo[ks], sc[c], 0, 0, 0);
      }
    }

    // ---- softmax: s = sc + bias, causal mask on diag tile ----
    const bool diag = (t == ntiles - 1);
    const int tile64 = t * 64;
#pragma unroll
    for (int c = 0; c < 4; c++) {
      f32x4 bb = *(const f32x4*)&sB[cur][16 * c + 4 * g];
      sc[c] += bb;                              // v_pk_add_f32
      if (diag) {
#pragma unroll
        for (int r = 0; r < 4; r++) {
          int key = tile64 + 32 * (c >> 1) + 8 * g + 4 * (c & 1) + r; // pi(slot)
          if (key > qg) sc[c][r] = -1e30f;
        }
      }
    }

    // ---- exact defer-max: rescale only if some score exceeds running max ----
    f32x4 mv = vmax4(vmax4(sc[0], sc[1]), vmax4(sc[2], sc[3]));
    float mloc = fmaxf(fmaxf(fmaxf(mv[0], mv[1]), mv[2]), mv[3]); // v_max3 fuse
    if (!__all(mloc <= m)) {                    // ~never taken (sink pins m=0)
      float mt = fmaxf(mloc, __shfl_xor(mloc, 16, 64));
      mt = fmaxf(mt, __shfl_xor(mt, 32, 64));
      float dm = fmaxf(mt - m, 0.0f);           // per-query, exact
      m += dm;
      float alpha = exp2f(-dm);
      l4 *= alpha;
#pragma unroll
      for (int db = 0; db < 4; db++) oacc[db] *= alpha;
    }

    // ---- weights: e = exp2(s - m); m==0 fast path skips the subtract ----
    if (__all(m == 0.0f)) {
#pragma unroll
      for (int c = 0; c < 4; c++) {
#pragma unroll
        for (int r = 0; r < 4; r++) sc[c][r] = exp2f(sc[c][r]);
        l4 += sc[c];
      }
    } else {
#pragma unroll
      for (int c = 0; c < 4; c++) {
#pragma unroll
        for (int r = 0; r < 4; r++) sc[c][r] = exp2f(sc[c][r] - m);
        l4 += sc[c];
      }
    }

    // ---- P repack (local by slot-permutation construction) ----
    B8 t0, t1;
#pragma unroll
    for (int j = 0; j < 8; j++) {
      t0.b[j] = (__bf16)sc[(j >> 2)][j & 3];
      t1.b[j] = (__bf16)sc[2 + (j >> 2)][j & 3];
    }

    // ---- PV: O^T += V^T . P^T ----
#pragma unroll
    for (int db = 0; db < 4; db++) {
#pragma unroll
      for (int ks = 0; ks < 2; ks++) {
        int idx = (db * 16 + qi) * 64 + ((ks * 32 + g * 8) ^ ((qi & 7) << 3));
        bf16x8 av = *(const bf16x8*)&sV[cur][idx];
        oacc[db] = __builtin_amdgcn_mfma_f32_16x16x32_bf16(av, (ks ? t1.b : t0.b),
                                                           oacc[db], 0, 0, 0);
      }
    }
    __syncthreads();   // drains vmcnt (next tile landed) + LDS-read reuse fence
    cur ^= 1;
  }

  // ---- epilogue ----
  float lt = (l4[0] + l4[1]) + (l4[2] + l4[3]);
  lt += __shfl_xor(lt, 16, 64);
  lt += __shfl_xor(lt, 32, 64);
  float denom = lt + exp2f(-m);   // + sink weight
  float inv = 1.0f / denom;
  float* op = out + (bhN + qg) * DH;
#pragma unroll
  for (int db = 0; db < 4; db++) {
    float4 o;
    o.x = oacc[db][0] * inv;
    o.y = oacc[db][1] * inv;
    o.z = oacc[db][2] * inv;
    o.w = oacc[db][3] * inv;
    *(float4*)(op + db * 16 + 4 * g) = o;
  }
}

extern "C" void kernel_launch(void* const* d_in, const int* in_sizes, int n_in,
                              void* d_out, int out_size, void* d_ws, size_t ws_size,
                              hipStream_t stream) {
  (void)in_sizes; (void)n_in; (void)out_size; (void)ws_size;
  const float* q = (const float*)d_in[0];
  const float* k = (const float*)d_in[1];
  const float* v = (const float*)d_in[2];
  float* out = (float*)d_out;

  // ws layout: K images 8 MiB | V images 8 MiB | bias 256 KiB
  char* ws = (char*)d_ws;
  unsigned short* wsK = (unsigned short*)ws;
  unsigned short* wsV = (unsigned short*)(ws + (8u << 20));
  float*          wsB = (float*)(ws + (16u << 20));

  build_ws<<<dim3(32, NT), dim3(256), 0, stream>>>(k, v, wsK, wsV, wsB);
  attend_l2_flash<<<dim3(32, NT), dim3(256), 0, stream>>>(q, wsK, wsV, wsB, out);
}